// Round 5
// baseline (224.032 us; speedup 1.0000x reference)
//
#include <hip/hip_runtime.h>
#include <hip/hip_bf16.h>
#include <math.h>

// KAN 2-layer forward, MI355X (gfx950) — round 5.
//   prep_weights x2 : fold scaler, pad 7->8, bf16            (W1 4MB, W2 4MB)
//   expand_x        : x -> F1 features (8192 x 2048) bf16    (32MB)
//   kan_gemm1       : F1 @ W1^T + exact-GELU -> h f32 (32MB)
//   kan_gemm2       : expand(h) in-staging @ W2^T, split-K=4, atomicAdd.
// Both GEMMs: 128x128 tile, BK=64, depth-2 prefetch with COUNTED vmcnt
// (raw s_barrier, never vmcnt(0) in the main loop — T3/T4 from the catalog),
// G4 XOR swizzle slot^=(row&7) staged via pre-swizzled global source.

typedef __attribute__((ext_vector_type(8))) short bf16x8;   // 8 x bf16
typedef __attribute__((ext_vector_type(4))) float f32x4;

#define TOKENS 8192
#define D_IN   256
#define D_HID  1024

// ---- exact uniform-cubic-B-spline features (closed form) ----
__device__ __forceinline__ void kan_features(float x, float f[8]) {
    f[0] = x / (1.0f + __expf(-x));          // silu
    const float s = (x + 1.0f) * 1.5f + 3.0f;
    const float cf = floorf(s);
    const float u = s - cf;
    const int c = (int)cf;
    const float u2 = u * u, u3 = u2 * u;
    const float k6 = 1.0f / 6.0f;
    const float v3 = u3 * k6;
    const float v2 = (-3.0f * u3 + 3.0f * u2 + 3.0f * u + 1.0f) * k6;
    const float v1 = (3.0f * u3 - 6.0f * u2 + 4.0f) * k6;
    const float w1 = 1.0f - u;
    const float v0 = w1 * w1 * w1 * k6;
    const bool in = (s >= 0.0f) && (s < 9.0f);
#pragma unroll
    for (int j = 0; j < 6; ++j) {
        int d = c - j;
        float bv = (d == 0) ? v3 : (d == 1) ? v2 : (d == 2) ? v1 : (d == 3) ? v0 : 0.0f;
        f[1 + j] = in ? bv : 0.0f;
    }
    f[7] = 0.0f;
}

__device__ __forceinline__ void features_to_bf16(const float f[8], __hip_bfloat16 fb[8]) {
#pragma unroll
    for (int j = 0; j < 8; ++j) fb[j] = __float2bfloat16(f[j]);
}

// ---------------- weight prep ----------------
__global__ void prep_weights(const float* __restrict__ bw,
                             const float* __restrict__ sw,
                             const float* __restrict__ sc,
                             __hip_bfloat16* __restrict__ Waug, int total) {
    int idx = blockIdx.x * blockDim.x + threadIdx.x;
    if (idx >= total) return;
    float scl = sc[idx];
    __hip_bfloat16 row[8];
    row[0] = __float2bfloat16(bw[idx]);
#pragma unroll
    for (int j = 0; j < 6; ++j)
        row[1 + j] = __float2bfloat16(sw[idx * 6 + j] * scl);
    row[7] = __float2bfloat16(0.0f);
    *(bf16x8*)&Waug[(size_t)idx * 8] = *(bf16x8*)row;
}

// ---------------- x -> F1 features ----------------
__global__ void expand_x(const float* __restrict__ X, __hip_bfloat16* __restrict__ F,
                         int total) {
    int idx = blockIdx.x * blockDim.x + threadIdx.x;
    if (idx >= total) return;
    float f[8];
    kan_features(X[idx], f);
    __hip_bfloat16 fb[8];
    features_to_bf16(f, fb);
    *(bf16x8*)&F[(size_t)idx * 8] = *(bf16x8*)fb;
}

// swizzled LDS element offset (bf16 units): 128B rows, 8 x 16B slots
__device__ __forceinline__ int swz8(int row, int s) {
    return row * 64 + ((s ^ (row & 7)) * 8);
}

#define GLL(src, dst) __builtin_amdgcn_global_load_lds(                         \
    (const __attribute__((address_space(1))) void*)(src),                       \
    (__attribute__((address_space(3))) void*)(dst), 16, 0, 0)

// ---------------- GEMM1: H = GELU(F1 @ W1^T), 128x128, BK=64, counted-vmcnt ----
__global__ __launch_bounds__(256, 2)
void kan_gemm1(const __hip_bfloat16* __restrict__ A,
               const __hip_bfloat16* __restrict__ W,
               float* __restrict__ H) {
    constexpr int K = D_IN * 8;            // 2048
    constexpr int NT = K / 64;             // 32 k-tiles
    __shared__ __hip_bfloat16 Al[2][128 * 64];
    __shared__ __hip_bfloat16 Bl[2][128 * 64];

    const int tid = threadIdx.x;
    const int wid = tid >> 6, lane = tid & 63;
    const int wm = wid >> 1, wn = wid & 1;
    const int lr = lane & 15, lg = lane >> 4;
    const int n0 = blockIdx.x * 128, o0 = blockIdx.y * 128;

    // staging: 4 items/thread, item=(row,slot) row-major; swizzled SOURCE slot
    int srow[4], sslot[4];
#pragma unroll
    for (int p = 0; p < 4; ++p) {
        int item = tid + p * 256;
        srow[p] = item >> 3;
        sslot[p] = (item & 7) ^ (srow[p] & 7);
    }
    // fragment read offsets (swizzled), per k-slice ks
    int aoff[2][4], boff[2][4];
#pragma unroll
    for (int ks = 0; ks < 2; ++ks)
#pragma unroll
        for (int f = 0; f < 4; ++f) {
            int ar = wm * 64 + f * 16 + lr;
            int br = wn * 64 + f * 16 + lr;
            aoff[ks][f] = ar * 64 + (((ks * 4 + lg) ^ (ar & 7)) * 8);
            boff[ks][f] = br * 64 + (((ks * 4 + lg) ^ (br & 7)) * 8);
        }

    f32x4 acc[4][4] = {};

#define STG1(buf, kt)                                                           \
    do {                                                                        \
        _Pragma("unroll")                                                       \
        for (int p = 0; p < 4; ++p) {                                           \
            GLL(A + (size_t)(n0 + srow[p]) * K + (kt) * 64 + sslot[p] * 8,      \
                &Al[buf][(tid + p * 256) * 8]);                                 \
            GLL(W + (size_t)(o0 + srow[p]) * K + (kt) * 64 + sslot[p] * 8,      \
                &Bl[buf][(tid + p * 256) * 8]);                                 \
        }                                                                       \
    } while (0)

    STG1(0, 0);
    STG1(1, 1);
    for (int t = 0; t < NT; ++t) {
        const int cur = t & 1;
        // wait: everything except the newest 8 (= tile t+1's loads) -> tile t ready
        asm volatile("s_waitcnt vmcnt(8)" ::: "memory");
        __builtin_amdgcn_s_barrier();
        __builtin_amdgcn_sched_barrier(0);
#pragma unroll
        for (int ks = 0; ks < 2; ++ks) {
            bf16x8 af[4], bfr[4];
#pragma unroll
            for (int f = 0; f < 4; ++f) af[f] = *(const bf16x8*)&Al[cur][aoff[ks][f]];
#pragma unroll
            for (int f = 0; f < 4; ++f) bfr[f] = *(const bf16x8*)&Bl[cur][boff[ks][f]];
#pragma unroll
            for (int fm = 0; fm < 4; ++fm)
#pragma unroll
                for (int fn = 0; fn < 4; ++fn)
                    acc[fm][fn] = __builtin_amdgcn_mfma_f32_16x16x32_bf16(
                        af[fm], bfr[fn], acc[fm][fn], 0, 0, 0);
        }
        asm volatile("s_waitcnt lgkmcnt(0)" ::: "memory");
        __builtin_amdgcn_s_barrier();
        __builtin_amdgcn_sched_barrier(0);
        // stage tile t+2 into freed buffer; clamped dummy at tail keeps count invariant
        const int kn = (t + 2 < NT) ? t + 2 : NT - 1;
        STG1(cur, kn);
    }
#undef STG1
    // epilogue: exact GELU, f32 store
#pragma unroll
    for (int fm = 0; fm < 4; ++fm) {
#pragma unroll
        for (int fn = 0; fn < 4; ++fn) {
            int col = o0 + wn * 64 + fn * 16 + lr;
#pragma unroll
            for (int r = 0; r < 4; ++r) {
                int row = n0 + wm * 64 + fm * 16 + lg * 4 + r;
                float v = acc[fm][fn][r];
                H[(size_t)row * D_HID + col] = 0.5f * v * (1.0f + erff(v * 0.70710678118f));
            }
        }
    }
}

// ---------------- GEMM2: out += expand(h) @ W2^T, 128x128, BK=64, split-K=4 ----
__global__ __launch_bounds__(256, 2)
void kan_gemm2(const float* __restrict__ H,
               const __hip_bfloat16* __restrict__ W,
               float* __restrict__ Y) {
    constexpr int OUT = D_IN, KD = D_HID * 8;   // 8192
    constexpr int NTT = KD / 64;                // 128 k-tiles
    __shared__ __hip_bfloat16 Al[2][128 * 64];
    __shared__ __hip_bfloat16 Bl[2][128 * 64];

    const int tid = threadIdx.x;
    const int wid = tid >> 6, lane = tid & 63;
    const int wm = wid >> 1, wn = wid & 1;
    const int lr = lane & 15, lg = lane >> 4;
    const int n0 = blockIdx.x * 128, o0 = blockIdx.y * 128;

    const int per = NTT / gridDim.z;            // 32
    const int ks0 = blockIdx.z * per, ks1 = ks0 + per;

    // B staging: 4 items/thread, swizzled source
    int srow[4], sslot[4];
#pragma unroll
    for (int p = 0; p < 4; ++p) {
        int item = tid + p * 256;
        srow[p] = item >> 3;
        sslot[p] = (item & 7) ^ (srow[p] & 7);
    }
    // A feature staging: thread -> (row, 4 h-cols)
    const int frow = tid >> 1, fc0 = (tid & 1) * 4;
    const float* hp = H + (size_t)(n0 + frow) * D_HID + fc0;   // + t*8 per tile
    // fragment offsets
    int aoff[2][4], boff[2][4];
#pragma unroll
    for (int ks = 0; ks < 2; ++ks)
#pragma unroll
        for (int f = 0; f < 4; ++f) {
            int ar = wm * 64 + f * 16 + lr;
            int br = wn * 64 + f * 16 + lr;
            aoff[ks][f] = ar * 64 + (((ks * 4 + lg) ^ (ar & 7)) * 8);
            boff[ks][f] = br * 64 + (((ks * 4 + lg) ^ (br & 7)) * 8);
        }

    f32x4 acc[4][4] = {};

#define STG2B(buf, kt)                                                          \
    do {                                                                        \
        _Pragma("unroll")                                                       \
        for (int p = 0; p < 4; ++p)                                             \
            GLL(W + (size_t)(o0 + srow[p]) * KD + (kt) * 64 + sslot[p] * 8,     \
                &Bl[buf][(tid + p * 256) * 8]);                                 \
    } while (0)

#define FEAT2(buf, hv)                                                          \
    do {                                                                        \
        _Pragma("unroll")                                                       \
        for (int jj = 0; jj < 4; ++jj) {                                        \
            float ff[8]; __hip_bfloat16 fb[8];                                  \
            kan_features((hv)[jj], ff);                                         \
            features_to_bf16(ff, fb);                                           \
            int sl = (fc0 + jj) ^ (frow & 7);                                   \
            *(bf16x8*)&Al[buf][frow * 64 + sl * 8] = *(bf16x8*)fb;              \
        }                                                                       \
    } while (0)

    // prologue: tiles ks0, ks0+1 staged; h for tile ks0+2 in flight
    f32x4 hA = *(const f32x4*)(hp + (size_t)ks0 * 8);
    f32x4 hB = *(const f32x4*)(hp + (size_t)(ks0 + 1) * 8);
    FEAT2(0, hA);
    STG2B(0, ks0);
    FEAT2(1, hB);
    STG2B(1, ks0 + 1);
    f32x4 hC = *(const f32x4*)(hp + (size_t)((ks0 + 2 < ks1) ? ks0 + 2 : ks1 - 1) * 8);

    for (int t = ks0; t < ks1; ++t) {
        const int cur = t & 1;                   // ks0 = bz*32 is even
        // wait all but newest 5 (= tile t+1's 4 B-loads + h for t+2) -> tile t ready
        asm volatile("s_waitcnt vmcnt(5)" ::: "memory");
        __builtin_amdgcn_s_barrier();
        __builtin_amdgcn_sched_barrier(0);
#pragma unroll
        for (int ks = 0; ks < 2; ++ks) {
            bf16x8 af[4], bfr[4];
#pragma unroll
            for (int f = 0; f < 4; ++f) af[f] = *(const bf16x8*)&Al[cur][aoff[ks][f]];
#pragma unroll
            for (int f = 0; f < 4; ++f) bfr[f] = *(const bf16x8*)&Bl[cur][boff[ks][f]];
#pragma unroll
            for (int fm = 0; fm < 4; ++fm)
#pragma unroll
                for (int fn = 0; fn < 4; ++fn)
                    acc[fm][fn] = __builtin_amdgcn_mfma_f32_16x16x32_bf16(
                        af[fm], bfr[fn], acc[fm][fn], 0, 0, 0);
        }
        asm volatile("s_waitcnt lgkmcnt(0)" ::: "memory");
        __builtin_amdgcn_s_barrier();
        __builtin_amdgcn_sched_barrier(0);
        // stage tile t+2 (clamped dummy at tail; never read, keeps vm count invariant)
        const int kn = (t + 2 < ks1) ? t + 2 : ks1 - 1;
        FEAT2(cur, hC);                           // features of tile t+2 (h loaded 2 ahead)
        hC = *(const f32x4*)(hp + (size_t)((t + 3 < ks1) ? t + 3 : ks1 - 1) * 8);  // 1 vm
        STG2B(cur, kn);                           // 4 vm
    }
#undef STG2B
#undef FEAT2

    // epilogue: split-K atomic accumulate
#pragma unroll
    for (int fm = 0; fm < 4; ++fm) {
#pragma unroll
        for (int fn = 0; fn < 4; ++fn) {
            int col = o0 + wn * 64 + fn * 16 + lr;
#pragma unroll
            for (int r = 0; r < 4; ++r) {
                int row = n0 + wm * 64 + fm * 16 + lg * 4 + r;
                atomicAdd(&Y[(size_t)row * OUT + col], acc[fm][fn][r]);
            }
        }
    }
}

extern "C" void kernel_launch(void* const* d_in, const int* in_sizes, int n_in,
                              void* d_out, int out_size, void* d_ws, size_t ws_size,
                              hipStream_t stream) {
    const float* x   = (const float*)d_in[0];
    const float* bw1 = (const float*)d_in[1];
    const float* sw1 = (const float*)d_in[2];
    const float* sc1 = (const float*)d_in[3];
    const float* bw2 = (const float*)d_in[4];
    const float* sw2 = (const float*)d_in[5];
    const float* sc2 = (const float*)d_in[6];
    float* out = (float*)d_out;

    char* ws = (char*)d_ws;
    __hip_bfloat16* W1 = (__hip_bfloat16*)ws;                   // 4MB
    __hip_bfloat16* W2 = (__hip_bfloat16*)(ws + (4ull << 20));  // 4MB
    __hip_bfloat16* F1 = (__hip_bfloat16*)(ws + (8ull << 20));  // 32MB
    float*          Hb = (float*)(ws + (40ull << 20));          // 32MB

    if (ws_size < (72ull << 20)) return;

    const int totW = D_HID * D_IN;   // 262144
    prep_weights<<<(totW + 255) / 256, 256, 0, stream>>>(bw1, sw1, sc1, W1, totW);
    prep_weights<<<(totW + 255) / 256, 256, 0, stream>>>(bw2, sw2, sc2, W2, totW);

    hipMemsetAsync(d_out, 0, (size_t)out_size * sizeof(float), stream);

    const int totX = TOKENS * D_IN;  // 2M
    expand_x<<<(totX + 255) / 256, 256, 0, stream>>>(x, F1, totX);

    // GEMM1: (8192 x 2048) @ (1024 x 2048)^T + GELU -> Hb
    kan_gemm1<<<dim3(TOKENS / 128, D_HID / 128), 256, 0, stream>>>(F1, W1, Hb);

    // GEMM2: expand(Hb) @ (256 x 8192)^T, split-K=4, atomic into out
    kan_gemm2<<<dim3(TOKENS / 128, D_IN / 128, 4), 256, 0, stream>>>(Hb, W2, out);
}

// Round 6
// 142.192 us; speedup vs baseline: 1.5756x; 1.5756x over previous
//
#include <hip/hip_runtime.h>
#include <hip/hip_bf16.h>
#include <math.h>

// KAN 2-layer forward, MI355X (gfx950) — round 6.
//   prep_weights x2 : fold scaler, pad 7->8, bf16            (W1 4MB, W2 4MB)
//   expand_x        : x -> F1 features (8192 x 2048) bf16    (32MB)
//   kan_gemm1       : F1 @ W1^T + exact-GELU -> h f32 (32MB) [round-5 version,
//                     128x128, BK=64, counted vmcnt, ~48us]
//   kan_gemm2       : expand(h) in-staging @ W2^T. BM=64, BN=256 (full OUT,
//                     features computed exactly once), BK=64, split-K=8
//                     -> 1024 blocks = 4 blocks/CU = 16 waves/CU.
//                     NO atomics: coalesced f32x4 partial stores (64MB).
//   reduce_split    : sum 8 partial slices -> out (72MB traffic, ~13us).

typedef __attribute__((ext_vector_type(8))) short bf16x8;   // 8 x bf16
typedef __attribute__((ext_vector_type(4))) float f32x4;

#define TOKENS 8192
#define D_IN   256
#define D_HID  1024

// ---- exact uniform-cubic-B-spline features (closed form) ----
__device__ __forceinline__ void kan_features(float x, float f[8]) {
    f[0] = x * __builtin_amdgcn_rcpf(1.0f + __expf(-x));   // silu via v_rcp
    const float s = (x + 1.0f) * 1.5f + 3.0f;
    const float cf = floorf(s);
    const float u = s - cf;
    const int c = (int)cf;
    const float u2 = u * u, u3 = u2 * u;
    const float k6 = 1.0f / 6.0f;
    const float v3 = u3 * k6;
    const float v2 = (-3.0f * u3 + 3.0f * u2 + 3.0f * u + 1.0f) * k6;
    const float v1 = (3.0f * u3 - 6.0f * u2 + 4.0f) * k6;
    const float w1 = 1.0f - u;
    const float v0 = w1 * w1 * w1 * k6;
    const bool in = (s >= 0.0f) && (s < 9.0f);
#pragma unroll
    for (int j = 0; j < 6; ++j) {
        int d = c - j;
        float bv = (d == 0) ? v3 : (d == 1) ? v2 : (d == 2) ? v1 : (d == 3) ? v0 : 0.0f;
        f[1 + j] = in ? bv : 0.0f;
    }
    f[7] = 0.0f;
}

__device__ __forceinline__ void features_to_bf16(const float f[8], __hip_bfloat16 fb[8]) {
#pragma unroll
    for (int j = 0; j < 8; ++j) fb[j] = __float2bfloat16(f[j]);
}

// ---------------- weight prep ----------------
__global__ void prep_weights(const float* __restrict__ bw,
                             const float* __restrict__ sw,
                             const float* __restrict__ sc,
                             __hip_bfloat16* __restrict__ Waug, int total) {
    int idx = blockIdx.x * blockDim.x + threadIdx.x;
    if (idx >= total) return;
    float scl = sc[idx];
    __hip_bfloat16 row[8];
    row[0] = __float2bfloat16(bw[idx]);
#pragma unroll
    for (int j = 0; j < 6; ++j)
        row[1 + j] = __float2bfloat16(sw[idx * 6 + j] * scl);
    row[7] = __float2bfloat16(0.0f);
    *(bf16x8*)&Waug[(size_t)idx * 8] = *(bf16x8*)row;
}

// ---------------- x -> F1 features ----------------
__global__ void expand_x(const float* __restrict__ X, __hip_bfloat16* __restrict__ F,
                         int total) {
    int idx = blockIdx.x * blockDim.x + threadIdx.x;
    if (idx >= total) return;
    float f[8];
    kan_features(X[idx], f);
    __hip_bfloat16 fb[8];
    features_to_bf16(f, fb);
    *(bf16x8*)&F[(size_t)idx * 8] = *(bf16x8*)fb;
}

#define GLL(src, dst) __builtin_amdgcn_global_load_lds(                         \
    (const __attribute__((address_space(1))) void*)(src),                       \
    (__attribute__((address_space(3))) void*)(dst), 16, 0, 0)

// ---------------- GEMM1: H = GELU(F1 @ W1^T), 128x128, BK=64, counted-vmcnt ----
__global__ __launch_bounds__(256, 2)
void kan_gemm1(const __hip_bfloat16* __restrict__ A,
               const __hip_bfloat16* __restrict__ W,
               float* __restrict__ H) {
    constexpr int K = D_IN * 8;            // 2048
    constexpr int NT = K / 64;             // 32 k-tiles
    __shared__ __hip_bfloat16 Al[2][128 * 64];
    __shared__ __hip_bfloat16 Bl[2][128 * 64];

    const int tid = threadIdx.x;
    const int wid = tid >> 6, lane = tid & 63;
    const int wm = wid >> 1, wn = wid & 1;
    const int lr = lane & 15, lg = lane >> 4;
    const int n0 = blockIdx.x * 128, o0 = blockIdx.y * 128;

    int srow[4], sslot[4];
#pragma unroll
    for (int p = 0; p < 4; ++p) {
        int item = tid + p * 256;
        srow[p] = item >> 3;
        sslot[p] = (item & 7) ^ (srow[p] & 7);
    }
    int aoff[2][4], boff[2][4];
#pragma unroll
    for (int ks = 0; ks < 2; ++ks)
#pragma unroll
        for (int f = 0; f < 4; ++f) {
            int ar = wm * 64 + f * 16 + lr;
            int br = wn * 64 + f * 16 + lr;
            aoff[ks][f] = ar * 64 + (((ks * 4 + lg) ^ (ar & 7)) * 8);
            boff[ks][f] = br * 64 + (((ks * 4 + lg) ^ (br & 7)) * 8);
        }

    f32x4 acc[4][4] = {};

#define STG1(buf, kt)                                                           \
    do {                                                                        \
        _Pragma("unroll")                                                       \
        for (int p = 0; p < 4; ++p) {                                           \
            GLL(A + (size_t)(n0 + srow[p]) * K + (kt) * 64 + sslot[p] * 8,      \
                &Al[buf][(tid + p * 256) * 8]);                                 \
            GLL(W + (size_t)(o0 + srow[p]) * K + (kt) * 64 + sslot[p] * 8,      \
                &Bl[buf][(tid + p * 256) * 8]);                                 \
        }                                                                       \
    } while (0)

    STG1(0, 0);
    STG1(1, 1);
    for (int t = 0; t < NT; ++t) {
        const int cur = t & 1;
        asm volatile("s_waitcnt vmcnt(8)" ::: "memory");
        __builtin_amdgcn_s_barrier();
        __builtin_amdgcn_sched_barrier(0);
#pragma unroll
        for (int ks = 0; ks < 2; ++ks) {
            bf16x8 af[4], bfr[4];
#pragma unroll
            for (int f = 0; f < 4; ++f) af[f] = *(const bf16x8*)&Al[cur][aoff[ks][f]];
#pragma unroll
            for (int f = 0; f < 4; ++f) bfr[f] = *(const bf16x8*)&Bl[cur][boff[ks][f]];
#pragma unroll
            for (int fm = 0; fm < 4; ++fm)
#pragma unroll
                for (int fn = 0; fn < 4; ++fn)
                    acc[fm][fn] = __builtin_amdgcn_mfma_f32_16x16x32_bf16(
                        af[fm], bfr[fn], acc[fm][fn], 0, 0, 0);
        }
        asm volatile("s_waitcnt lgkmcnt(0)" ::: "memory");
        __builtin_amdgcn_s_barrier();
        __builtin_amdgcn_sched_barrier(0);
        const int kn = (t + 2 < NT) ? t + 2 : NT - 1;
        STG1(cur, kn);
    }
#undef STG1
#pragma unroll
    for (int fm = 0; fm < 4; ++fm) {
#pragma unroll
        for (int fn = 0; fn < 4; ++fn) {
            int col = o0 + wn * 64 + fn * 16 + lr;
#pragma unroll
            for (int r = 0; r < 4; ++r) {
                int row = n0 + wm * 64 + fm * 16 + lg * 4 + r;
                float v = acc[fm][fn][r];
                H[(size_t)row * D_HID + col] = 0.5f * v * (1.0f + erff(v * 0.70710678118f));
            }
        }
    }
}

// ---------------- GEMM2: P[z] = expand(h) @ W2^T slice, no atomics ----------------
// BM=64, BN=256, BK=64 (8 h-cols/tile), split-K=8, 4 blocks/CU.
__global__ __launch_bounds__(256, 4)
void kan_gemm2(const float* __restrict__ H,
               const __hip_bfloat16* __restrict__ W,
               float* __restrict__ P) {
    constexpr int OUT = D_IN, KD = D_HID * 8;   // 8192
    constexpr int NTT = KD / 64;                // 128 k-tiles
    __shared__ __hip_bfloat16 Al[64 * 64];      // 8KB
    __shared__ __hip_bfloat16 Bl[256 * 64];     // 32KB

    const int tid = threadIdx.x;
    const int wid = tid >> 6, lane = tid & 63;
    const int lr = lane & 15, lg = lane >> 4;
    const int n0 = blockIdx.x * 64;

    const int per = NTT / 8;                    // 16
    const int ks0 = blockIdx.z * per, ks1 = ks0 + per;

    // B staging: 8 items/thread (256 rows x 8 slots), swizzled source slot
    int srow[8], sslot[8];
#pragma unroll
    for (int p = 0; p < 8; ++p) {
        int item = tid + p * 256;
        srow[p] = item >> 3;
        sslot[p] = (item & 7) ^ (srow[p] & 7);
    }
    // A features: 2 items/thread: rows ar0, ar0+32; h-col = ac (0..7) within tile
    const int ar0 = tid >> 3, ac = tid & 7;
    const float* hp0 = H + (size_t)(n0 + ar0) * D_HID + ac;
    const float* hp1 = H + (size_t)(n0 + ar0 + 32) * D_HID + ac;
    const int aw0 = ar0 * 64 + ((ac ^ (ar0 & 7)) * 8);
    const int aw1 = (ar0 + 32) * 64 + ((ac ^ (ar0 & 7)) * 8);

    int aoff[2][4], boff[2][4];
#pragma unroll
    for (int ks = 0; ks < 2; ++ks)
#pragma unroll
        for (int f = 0; f < 4; ++f) {
            int ar = f * 16 + lr;
            int br = wid * 64 + f * 16 + lr;
            aoff[ks][f] = ar * 64 + (((ks * 4 + lg) ^ (ar & 7)) * 8);
            boff[ks][f] = br * 64 + (((ks * 4 + lg) ^ (br & 7)) * 8);
        }

    f32x4 acc[4][4] = {};

    float hv0 = hp0[(size_t)ks0 * 8];
    float hv1 = hp1[(size_t)ks0 * 8];

    for (int kt = ks0; kt < ks1; ++kt) {
        float hc0 = hv0, hc1 = hv1;
        const int knext = (kt + 1 < ks1) ? kt + 1 : ks1 - 1;
        hv0 = hp0[(size_t)knext * 8];
        hv1 = hp1[(size_t)knext * 8];
        // A: features -> swizzled ds_write
        {
            float ff[8]; __hip_bfloat16 fb[8];
            kan_features(hc0, ff); features_to_bf16(ff, fb);
            *(bf16x8*)&Al[aw0] = *(bf16x8*)fb;
            kan_features(hc1, ff); features_to_bf16(ff, fb);
            *(bf16x8*)&Al[aw1] = *(bf16x8*)fb;
        }
        // B: 8 global_load_lds (pre-swizzled source)
#pragma unroll
        for (int p = 0; p < 8; ++p)
            GLL(W + (size_t)srow[p] * KD + (size_t)kt * 64 + sslot[p] * 8,
                &Bl[(tid + p * 256) * 8]);
        __syncthreads();
#pragma unroll
        for (int ks = 0; ks < 2; ++ks) {
            bf16x8 af[4], bfr[4];
#pragma unroll
            for (int f = 0; f < 4; ++f) af[f] = *(const bf16x8*)&Al[aoff[ks][f]];
#pragma unroll
            for (int f = 0; f < 4; ++f) bfr[f] = *(const bf16x8*)&Bl[boff[ks][f]];
#pragma unroll
            for (int fm = 0; fm < 4; ++fm)
#pragma unroll
                for (int fn = 0; fn < 4; ++fn)
                    acc[fm][fn] = __builtin_amdgcn_mfma_f32_16x16x32_bf16(
                        af[fm], bfr[fn], acc[fm][fn], 0, 0, 0);
        }
        __syncthreads();
    }

    // ---- epilogue: transpose via LDS (reuse Bl), coalesced f32x4 partial stores ----
    float* Pl = (float*)Bl;                      // 64 x 128 f32 = 32KB
    const size_t zoff = (size_t)blockIdx.z * TOKENS * OUT;
#pragma unroll
    for (int h = 0; h < 2; ++h) {
        __syncthreads();
        if ((wid >> 1) == h) {
#pragma unroll
            for (int fm = 0; fm < 4; ++fm)
#pragma unroll
                for (int fn = 0; fn < 4; ++fn) {
                    int c = (wid & 1) * 64 + fn * 16 + lr;
#pragma unroll
                    for (int r = 0; r < 4; ++r)
                        Pl[(fm * 16 + lg * 4 + r) * 128 + c] = acc[fm][fn][r];
                }
        }
        __syncthreads();
#pragma unroll
        for (int q = 0; q < 8; ++q) {
            int v = tid + q * 256;               // 0..2047
            int row = v >> 5, cv = (v & 31) * 4;
            *(f32x4*)&P[zoff + (size_t)(n0 + row) * OUT + h * 128 + cv] =
                *(const f32x4*)&Pl[row * 128 + cv];
        }
    }
}

// ---------------- reduce 8 partial slices -> out ----------------
__global__ void reduce_split(const float* __restrict__ P, float* __restrict__ out,
                             int nvec) {
    int i = blockIdx.x * 256 + threadIdx.x;
    if (i >= nvec) return;
    const f32x4* Pv = (const f32x4*)P;
    f32x4 s = Pv[i];
#pragma unroll
    for (int z = 1; z < 8; ++z) s += Pv[(size_t)z * nvec + i];
    ((f32x4*)out)[i] = s;
}

extern "C" void kernel_launch(void* const* d_in, const int* in_sizes, int n_in,
                              void* d_out, int out_size, void* d_ws, size_t ws_size,
                              hipStream_t stream) {
    const float* x   = (const float*)d_in[0];
    const float* bw1 = (const float*)d_in[1];
    const float* sw1 = (const float*)d_in[2];
    const float* sc1 = (const float*)d_in[3];
    const float* bw2 = (const float*)d_in[4];
    const float* sw2 = (const float*)d_in[5];
    const float* sc2 = (const float*)d_in[6];
    float* out = (float*)d_out;

    char* ws = (char*)d_ws;
    __hip_bfloat16* W1 = (__hip_bfloat16*)ws;                   // 4MB
    __hip_bfloat16* W2 = (__hip_bfloat16*)(ws + (4ull << 20));  // 4MB
    __hip_bfloat16* F1 = (__hip_bfloat16*)(ws + (8ull << 20));  // 32MB
    float*          Hb = (float*)(ws + (40ull << 20));          // 32MB
    float*          Pp = (float*)(ws + (72ull << 20));          // 64MB

    if (ws_size < (136ull << 20)) return;

    const int totW = D_HID * D_IN;   // 262144
    prep_weights<<<(totW + 255) / 256, 256, 0, stream>>>(bw1, sw1, sc1, W1, totW);
    prep_weights<<<(totW + 255) / 256, 256, 0, stream>>>(bw2, sw2, sc2, W2, totW);

    const int totX = TOKENS * D_IN;  // 2M
    expand_x<<<(totX + 255) / 256, 256, 0, stream>>>(x, F1, totX);

    // GEMM1: (8192 x 2048) @ (1024 x 2048)^T + GELU -> Hb
    kan_gemm1<<<dim3(TOKENS / 128, D_HID / 128), 256, 0, stream>>>(F1, W1, Hb);

    // GEMM2: expand(Hb) @ (256 x 8192)^T -> 8 partial slices
    kan_gemm2<<<dim3(TOKENS / 64, 1, 8), 256, 0, stream>>>(Hb, W2, Pp);

    // Reduce partials -> out
    const int nvec = TOKENS * D_IN / 4;  // 524288
    reduce_split<<<(nvec + 255) / 256, 256, 0, stream>>>(Pp, out, nvec);
}